// Round 6
// baseline (7659.917 us; speedup 1.0000x reference)
//
#include <hip/hip_runtime.h>
#include <hip/hip_cooperative_groups.h>
#include <math.h>

namespace cg = cooperative_groups;

#define NTOT  4194304      // 32*32*32*128
#define N4    1048576
#define N8    524288
#define KDIM  1152         // 9 taps * 128 cin
#define GRID  256          // 1 block/CU; each block does 2 work items
#define BLK   1024         // 16 waves -> 4 waves/SIMD
#define NTH   (GRID*BLK)

typedef unsigned short u16;
typedef __attribute__((ext_vector_type(8))) short short8v;   // 8 bf16
typedef __attribute__((ext_vector_type(4))) float float4v;   // MFMA acc

__device__ inline float b2f(u16 u) { union { unsigned int i; float f; } x; x.i = ((unsigned int)u) << 16; return x.f; }
__device__ inline u16   f2b(float f) {
    union { unsigned int i; float f; } x; x.f = f;
    unsigned int u = x.i;
    return (u16)((u + 0x7fffu + ((u >> 16) & 1u)) >> 16);   // RNE
}
__device__ inline void ld8(const u16* __restrict__ p, float* v) {
    uint4 r = *(const uint4*)p;
    v[0] = b2f((u16)(r.x & 0xffff)); v[1] = b2f((u16)(r.x >> 16));
    v[2] = b2f((u16)(r.y & 0xffff)); v[3] = b2f((u16)(r.y >> 16));
    v[4] = b2f((u16)(r.z & 0xffff)); v[5] = b2f((u16)(r.z >> 16));
    v[6] = b2f((u16)(r.w & 0xffff)); v[7] = b2f((u16)(r.w >> 16));
}
__device__ inline uint4 pk8(const float* v) {
    uint4 o;
    o.x = (unsigned int)f2b(v[0]) | ((unsigned int)f2b(v[1]) << 16);
    o.y = (unsigned int)f2b(v[2]) | ((unsigned int)f2b(v[3]) << 16);
    o.z = (unsigned int)f2b(v[4]) | ((unsigned int)f2b(v[5]) << 16);
    o.w = (unsigned int)f2b(v[6]) | ((unsigned int)f2b(v[7]) << 16);
    return o;
}
__device__ inline void fma8(float* __restrict__ v, const u16* __restrict__ p, float s) {
    float kv[8];
    ld8(p, kv);
    #pragma unroll
    for (int j = 0; j < 8; ++j) v[j] = fmaf(s, kv[j], v[j]);
}
__device__ inline float ld_acq(const float* p) {
    return __hip_atomic_load(p, __ATOMIC_ACQUIRE, __HIP_MEMORY_SCOPE_AGENT);
}
__device__ inline void st_rel(float* p, float v) {
    __hip_atomic_store(p, v, __ATOMIC_RELEASE, __HIP_MEMORY_SCOPE_AGENT);
}

// Butcher tableau
constexpr float A21 = 0.2f;
constexpr float A31 = (float)(3.0/40.0),       A32 = (float)(9.0/40.0);
constexpr float A41 = (float)(44.0/45.0),      A42 = (float)(-56.0/15.0),      A43 = (float)(32.0/9.0);
constexpr float A51 = (float)(19372.0/6561.0), A52 = (float)(-25360.0/2187.0), A53 = (float)(64448.0/6561.0), A54 = (float)(-212.0/729.0);
constexpr float A61 = (float)(9017.0/3168.0),  A62 = (float)(-355.0/33.0),     A63 = (float)(46732.0/5247.0), A64 = (float)(49.0/176.0), A65 = (float)(-5103.0/18656.0);
constexpr float B1c = (float)(35.0/384.0),     B3c = (float)(500.0/1113.0),    B4c = (float)(125.0/192.0),    B5c = (float)(-2187.0/6784.0), B6c = (float)(11.0/84.0);
constexpr float CF2 = 0.2f, CF3 = 0.3f, CF4 = 0.8f, CF5 = (float)(8.0/9.0);

// ========================= persistent cooperative path =====================
// Block = 1024 threads = 16 waves. Per work item (8x8 spatial tile, one img):
//   staging: 12x12 halo x 128ch -> ldsA (bf16, XOR-swizzled)
//   conv1:   M=128-pad (10x10 h-positions) x N=128; wave grid 8M x 2N,
//            4 N-frags/wave -> ldsH
//   conv2:   M=64 (inner 8x8) x N=128; wave grid 4M x 4N, 2 N-frags/wave
//            -> global kout
template<int NK, bool STY5>
__device__ __forceinline__ void feval(
    char* ldsA, char* ldsH,
    const float* __restrict__ yb, float* __restrict__ y5b,
    const u16* __restrict__ ka, const u16* __restrict__ kb,
    const u16* __restrict__ kc, const u16* __restrict__ kd,
    const u16* __restrict__ ke,
    float ca, float cb, float cc, float cd, float ce,
    const short* __restrict__ Wt1, const float* __restrict__ b1g, const float* __restrict__ E1g,
    const short* __restrict__ Wt2, const float* __restrict__ b2g, const float* __restrict__ E2g,
    u16* __restrict__ kout,
    float tcur, float dt, float tfrac,
    int img, int ty, int tx, int tid)
{
    const size_t ibase = (size_t)img * 131072;
    const float tval = tcur + tfrac * dt;

    // ---- staging: 144 pos x 16 ch-groups ----
    {
        const float s1 = dt*ca, s2 = dt*cb, s3 = dt*cc, s4 = dt*cd, s5 = dt*ce;
        for (int i = tid; i < 144*16; i += BLK) {
            const int pos = i >> 4, ch8 = i & 15;
            const int iy = pos / 12, ix = pos - iy*12;
            const int gy = ty + iy - 2, gx = tx + ix - 2;
            uint4 w128 = make_uint4(0u, 0u, 0u, 0u);
            if ((unsigned)gy < 32u && (unsigned)gx < 32u) {
                const size_t idx = ibase + (size_t)((gy << 5) + gx)*128 + ch8*8;
                float v[8];
                *(float4*)(v)     = *(const float4*)(yb + idx);
                *(float4*)(v + 4) = *(const float4*)(yb + idx + 4);
                if (NK >= 1) fma8(v, ka + idx, s1);
                if (NK >= 2) fma8(v, kb + idx, s2);
                if (NK >= 3) fma8(v, kc + idx, s3);
                if (NK >= 4) fma8(v, kd + idx, s4);
                if (NK >= 5) fma8(v, ke + idx, s5);
                if (STY5) {
                    if ((unsigned)(iy - 2) < 8u && (unsigned)(ix - 2) < 8u) {
                        *(float4*)(y5b + idx)     = *(const float4*)(v);
                        *(float4*)(y5b + idx + 4) = *(const float4*)(v + 4);
                    }
                }
                w128 = pk8(v);
            }
            *(uint4*)(ldsA + pos*256 + ((ch8*16) ^ ((pos & 7) << 4))) = w128;
        }
    }
    __syncthreads();

    const int l  = tid & 63, w = tid >> 6;     // w = 0..15
    const int lr = l & 15,  kg = l >> 4;

    // ---- conv1: wave grid 8M x 2N; each wave 1 M-frag x 4 N-frags ----
    {
        const int mf = w >> 1;                 // 0..7
        const int nh = (w & 1) * 4;            // N-frag base (0 or 4)
        float4v acc[4];
        #pragma unroll
        for (int cf = 0; cf < 4; ++cf) acc[cf] = (float4v){0.f, 0.f, 0.f, 0.f};
        const int p0 = mf*16 + lr;
        const int py = p0 / 10, px = p0 - (p0/10)*10;

        #pragma unroll 1
        for (int ky = 0; ky < 3; ++ky) {
            #pragma unroll 1
            for (int kx = 0; kx < 3; ++kx) {
                const int tap = ky*3 + kx;
                #pragma unroll
                for (int kk = 0; kk < 4; ++kk) {
                    int pp = (py + ky)*12 + px + kx;
                    pp = (pp < 144) ? pp : 143;
                    short8v a = *(const short8v*)(ldsA + pp*256 + ((16*(kk*4 + kg)) ^ ((pp & 7) << 4)));
                    const short* wb = Wt1 + tap*128 + kk*32 + kg*8;
                    short8v bb[4];
                    #pragma unroll
                    for (int cf = 0; cf < 4; ++cf)
                        bb[cf] = *(const short8v*)(wb + (size_t)((nh + cf)*16 + lr)*KDIM);
                    #pragma unroll
                    for (int cf = 0; cf < 4; ++cf)
                        acc[cf] = __builtin_amdgcn_mfma_f32_16x16x32_bf16(a, bb[cf], acc[cf], 0, 0, 0);
                }
            }
        }
        // epilogue -> ldsH
        #pragma unroll
        for (int ri = 0; ri < 4; ++ri) {
            const int p = mf*16 + kg*4 + ri;
            if (p < 100) {
                const int hy = p / 10, hx = p - (p/10)*10;
                const int gy = ty + hy - 1, gx = tx + hx - 1;
                const bool in = ((unsigned)gy < 32u) && ((unsigned)gx < 32u);
                const int cy = (gy == 0) ? 0 : ((gy == 31) ? 2 : 1);
                const int cx = (gx == 0) ? 0 : ((gx == 31) ? 2 : 1);
                const int ecl = (cy*3 + cx)*128;
                #pragma unroll
                for (int cf = 0; cf < 4; ++cf) {
                    const int c = (nh + cf)*16 + lr;
                    float v = 0.f;
                    if (in) v = fmaxf(acc[cf][ri] + b1g[c] + tval*E1g[ecl + c], 0.f);
                    *(u16*)(ldsH + p*256 + ((2*c) ^ ((p & 7) << 4))) = f2b(v);
                }
            }
        }
    }
    __syncthreads();

    // ---- conv2: wave grid 4M x 4N; each wave 1 M-frag x 2 N-frags ----
    {
        const int mf = w >> 2;                 // 0..3
        const int nq = (w & 3) * 2;            // N-frag base
        float4v acc[2];
        acc[0] = (float4v){0.f, 0.f, 0.f, 0.f};
        acc[1] = (float4v){0.f, 0.f, 0.f, 0.f};
        const int r = mf*16 + lr;
        const int oy = r >> 3, ox = r & 7;
        #pragma unroll 1
        for (int ky = 0; ky < 3; ++ky) {
            #pragma unroll 1
            for (int kx = 0; kx < 3; ++kx) {
                const int tap = ky*3 + kx;
                #pragma unroll
                for (int kk = 0; kk < 4; ++kk) {
                    const int p = (oy + ky)*10 + ox + kx;
                    short8v a = *(const short8v*)(ldsH + p*256 + ((16*(kk*4 + kg)) ^ ((p & 7) << 4)));
                    const short* wb = Wt2 + tap*128 + kk*32 + kg*8;
                    short8v b0 = *(const short8v*)(wb + (size_t)((nq + 0)*16 + lr)*KDIM);
                    short8v b1v = *(const short8v*)(wb + (size_t)((nq + 1)*16 + lr)*KDIM);
                    acc[0] = __builtin_amdgcn_mfma_f32_16x16x32_bf16(a, b0,  acc[0], 0, 0, 0);
                    acc[1] = __builtin_amdgcn_mfma_f32_16x16x32_bf16(a, b1v, acc[1], 0, 0, 0);
                }
            }
        }
        #pragma unroll
        for (int ri = 0; ri < 4; ++ri) {
            const int r2  = mf*16 + kg*4 + ri;
            const int gy  = ty + (r2 >> 3), gx = tx + (r2 & 7);
            const int cy  = (gy == 0) ? 0 : ((gy == 31) ? 2 : 1);
            const int cx  = (gx == 0) ? 0 : ((gx == 31) ? 2 : 1);
            const int ecl = (cy*3 + cx)*128;
            const size_t obase = ibase + (size_t)((gy << 5) + gx)*128;
            #pragma unroll
            for (int cf = 0; cf < 2; ++cf) {
                const int c = (nq + cf)*16 + lr;
                float v = fmaxf(acc[cf][ri] + b2g[c] + tval*E2g[ecl + c], 0.f);
                kout[obase + c] = f2b(v);
            }
        }
    }
}

__device__ __forceinline__ void err_phase(
    const float* __restrict__ y, const float* __restrict__ y5,
    const u16* __restrict__ k1, const u16* __restrict__ k3,
    const u16* __restrict__ k4, const u16* __restrict__ k5,
    const u16* __restrict__ k6, const u16* __restrict__ k7,
    float dt, double* __restrict__ slot, char* lds, int gtid, int tid)
{
    const float ER1 = (float)(35.0/384.0 - 5179.0/57600.0);
    const float ER3 = (float)(500.0/1113.0 - 7571.0/16695.0);
    const float ER4 = (float)(125.0/192.0 - 393.0/640.0);
    const float ER5 = (float)(-2187.0/6784.0 + 92097.0/339200.0);
    const float ER6 = (float)(11.0/84.0 - 187.0/2100.0);
    const float ER7 = (float)(-1.0/40.0);
    float lsum = 0.f;
    for (int i = gtid; i < N8; i += NTH) {
        const size_t base = (size_t)i * 8;
        float a[8], c[8], d[8], e[8], f[8], g[8], yv[8], v5[8];
        ld8(k1 + base, a); ld8(k3 + base, c); ld8(k4 + base, d);
        ld8(k5 + base, e); ld8(k6 + base, f); ld8(k7 + base, g);
        *(float4*)(yv)     = *(const float4*)(y + base);
        *(float4*)(yv + 4) = *(const float4*)(y + base + 4);
        *(float4*)(v5)     = *(const float4*)(y5 + base);
        *(float4*)(v5 + 4) = *(const float4*)(y5 + base + 4);
        #pragma unroll
        for (int j = 0; j < 8; ++j) {
            float err = dt*(ER1*a[j] + ER3*c[j] + ER4*d[j] + ER5*e[j] + ER6*f[j] + ER7*g[j]);
            float sc  = 1e-3f + 1e-3f*fmaxf(fabsf(yv[j]), fabsf(v5[j]));
            float rr = err/sc; lsum += rr*rr;
        }
    }
    #pragma unroll
    for (int off = 32; off > 0; off >>= 1) lsum += __shfl_down(lsum, off, 64);
    float* ws16 = (float*)lds;
    const int wid = tid >> 6, lane = tid & 63;
    if (lane == 0) ws16[wid] = lsum;
    __syncthreads();
    if (tid == 0) {
        float bs = 0.f;
        #pragma unroll
        for (int i = 0; i < BLK/64; ++i) bs += ws16[i];
        atomicAdd(slot, (double)bs);
    }
    __syncthreads();
}

__device__ void ctrl_body(float* st, double a)
{
    float t = st[0], dt = st[1], dtc = st[2];
    bool done = (st[3] != 0.0f);
    float en = sqrtf((float)(a / (double)NTOT));
    en = fmaxf(en, 1e-10f);
    bool accept = (en <= 1.0f);
    float factor = fminf(fmaxf(0.9f * powf(en, -0.2f), 0.2f), 10.0f);
    bool adv = accept && !done;
    if (adv) t += dtc;
    if (!done) dt = dtc * factor;
    done = done || (t >= 1.0f - 1e-6f);
    st_rel(st + 0, t); st_rel(st + 1, dt);
    st_rel(st + 3, done ? 1.0f : 0.0f); st_rel(st + 4, adv ? 1.0f : 0.0f);
    st_rel(st + 2, fminf(dt, 1.0f - t));
}

#define DO_STAGE(NKv, STY5v, KA,KB,KC,KD,KE, CA,CB,CC,CD,CE, KOUT, TF)           \
    _Pragma("unroll 1")                                                          \
    for (int h2 = 0; h2 < 2; ++h2) {                                             \
        const int wi  = bid + (h2 << 8);                                         \
        feval<NKv,STY5v>(ldsA, ldsH, ycur, yalt, KA,KB,KC,KD,KE,                 \
                         CA,CB,CC,CD,CE, Wt1,b1,E1t, Wt2,b2,E2t, KOUT,           \
                         t, dt, TF, wi >> 4, ((wi >> 2) & 3)*8, (wi & 3)*8, tid);\
    }                                                                            \
    gg.sync();

__global__ __launch_bounds__(BLK) void ode_persist(
    const float* __restrict__ x,
    const float* __restrict__ w1, const float* __restrict__ b1,
    const float* __restrict__ w2, const float* __restrict__ b2,
    char* __restrict__ ws, float* __restrict__ outp)
{
    __shared__ __align__(16) char ldsA[144*256];   // 36864 B
    __shared__ __align__(16) char ldsH[100*256];   // 25600 B

    cg::grid_group gg = cg::this_grid();

    double* acc = (double*)ws;
    float*  st  = (float*)(ws + 256);
    float*  E1t = (float*)(ws + 512);
    float*  E2t = (float*)(ws + 5120);
    short*  Wt1 = (short*)(ws + 10240);
    short*  Wt2 = (short*)(ws + 305152);
    char*   bufs = ws + 1048576;
    float* yA = (float*)(bufs);
    float* yB = (float*)(bufs + (size_t)NTOT*4);
    u16* k1 = (u16*)(bufs + (size_t)NTOT*8);
    u16* k2 = (u16*)(bufs + (size_t)NTOT*10);
    u16* k3 = (u16*)(bufs + (size_t)NTOT*12);
    u16* k4 = (u16*)(bufs + (size_t)NTOT*14);
    u16* k5 = (u16*)(bufs + (size_t)NTOT*16);
    u16* k6 = (u16*)(bufs + (size_t)NTOT*18);
    u16* k7 = (u16*)(bufs + (size_t)NTOT*20);

    const int tid  = threadIdx.x;
    const int bid  = blockIdx.x;
    const int gtid = bid*BLK + tid;

    // ---- prologue ----
    for (int i = gtid; i < 9*128*128; i += NTH) {
        const int tap = i >> 14, r = i & 16383;
        const int ci = r >> 7, co = r & 127;
        Wt1[co*KDIM + tap*128 + ci] = (short)f2b(w1[(tap*129 + ci)*128 + co]);
        Wt2[co*KDIM + tap*128 + ci] = (short)f2b(w2[(tap*129 + ci)*128 + co]);
    }
    for (int i = gtid; i < 9*128; i += NTH) {
        const int cls = i >> 7, co = i & 127;
        const int cy = cls / 3, cx = cls - cy*3;
        float s1 = 0.f, s2 = 0.f;
        for (int ky = 0; ky < 3; ++ky) {
            if ((cy == 0 && ky == 0) || (cy == 2 && ky == 2)) continue;
            for (int kx = 0; kx < 3; ++kx) {
                if ((cx == 0 && kx == 0) || (cx == 2 && kx == 2)) continue;
                s1 += w1[((ky*3 + kx)*129 + 128)*128 + co];
                s2 += w2[((ky*3 + kx)*129 + 128)*128 + co];
            }
        }
        E1t[cls*128 + co] = s1;
        E2t[cls*128 + co] = s2;
    }
    for (int i = gtid; i < N4; i += NTH)
        ((float4*)yA)[i] = ((const float4*)x)[i];
    if (gtid == 0) {
        st[0] = 0.f; st[1] = 0.05f; st[2] = 0.05f; st[3] = 0.f; st[4] = 0.f;
        for (int i = 0; i < 32; ++i) acc[i] = 0.0;
    }
    gg.sync();

    float* ycur = yA;
    float* yalt = yB;

    for (int it = 0; it < 32; ++it) {
        if (ld_acq(st + 3) != 0.0f) break;
        const float t = ld_acq(st + 0), dt = ld_acq(st + 2);

        DO_STAGE(0,false, k1,k1,k1,k1,k1, 0,0,0,0,0,                  k1, 0.0f)
        DO_STAGE(1,false, k1,k1,k1,k1,k1, A21,0,0,0,0,                k2, CF2)
        DO_STAGE(2,false, k1,k2,k2,k2,k2, A31,A32,0,0,0,              k3, CF3)
        DO_STAGE(3,false, k1,k2,k3,k3,k3, A41,A42,A43,0,0,            k4, CF4)
        DO_STAGE(4,false, k1,k2,k3,k4,k4, A51,A52,A53,A54,0,          k5, CF5)
        DO_STAGE(5,false, k1,k2,k3,k4,k5, A61,A62,A63,A64,A65,        k6, 1.0f)
        DO_STAGE(5,true,  k1,k3,k4,k5,k6, B1c,B3c,B4c,B5c,B6c,        k7, 1.0f)

        err_phase(ycur, yalt, k1, k3, k4, k5, k6, k7, dt, acc + it, ldsA, gtid, tid);
        gg.sync();
        if (gtid == 0) ctrl_body(st, acc[it]);
        gg.sync();
        if (ld_acq(st + 4) != 0.0f) { float* tmp = ycur; ycur = yalt; yalt = tmp; }
    }

    for (int i = gtid; i < N4; i += NTH)
        ((float4*)outp)[i] = ((const float4*)ycur)[i];
}

// ============================ fallback path (round-3) ======================

__global__ __launch_bounds__(64) void init_kernel(float* __restrict__ st, double* __restrict__ acc)
{
    int i = threadIdx.x;
    if (i < 32) acc[i] = 0.0;
    if (i == 0) { st[0]=0.0f; st[1]=0.05f; st[2]=0.05f; st[3]=0.0f; st[4]=0.0f; }
}

__global__ __launch_bounds__(256) void prep_kernel(
    const float* __restrict__ w, short* __restrict__ Wt, float* __restrict__ Et)
{
    const int part = blockIdx.x;
    const int tid = threadIdx.x;
    if (part < 9) {
        const int tap = part;
        for (int i = tid; i < 128*128; i += 256) {
            const int ci = i >> 7, co = i & 127;
            Wt[co*KDIM + tap*128 + ci] = (short)f2b(w[(tap*129 + ci)*128 + co]);
        }
    } else {
        for (int i = tid; i < 9*128; i += 256) {
            const int cls = i >> 7, co = i & 127;
            const int cy = cls / 3, cx = cls % 3;
            float s = 0.f;
            for (int ky = 0; ky < 3; ++ky) {
                if ((cy==0 && ky==0) || (cy==2 && ky==2)) continue;
                for (int kx = 0; kx < 3; ++kx) {
                    if ((cx==0 && kx==0) || (cx==2 && kx==2)) continue;
                    s += w[((ky*3+kx)*129 + 128)*128 + co];
                }
            }
            Et[cls*128 + co] = s;
        }
    }
}

__global__ __launch_bounds__(256) void copy_kernel(float* __restrict__ dst, const float* __restrict__ src)
{
    int stride = gridDim.x * blockDim.x;
    for (int i = blockIdx.x*blockDim.x + threadIdx.x; i < N4; i += stride)
        reinterpret_cast<float4*>(dst)[i] = reinterpret_cast<const float4*>(src)[i];
}

__global__ __launch_bounds__(256) void copy_if_adv_kernel(float* __restrict__ dst,
                                                          const float* __restrict__ src,
                                                          const float* __restrict__ st)
{
    if (st[4] == 0.0f) return;
    int stride = gridDim.x * blockDim.x;
    for (int i = blockIdx.x*blockDim.x + threadIdx.x; i < N4; i += stride)
        reinterpret_cast<float4*>(dst)[i] = reinterpret_cast<const float4*>(src)[i];
}

template<int NK>
__global__ __launch_bounds__(256) void conv_mfma(
    const float* __restrict__ basef, const u16* __restrict__ bfin,
    const u16* __restrict__ ka, const u16* __restrict__ kb,
    const u16* __restrict__ kc, const u16* __restrict__ kd,
    const u16* __restrict__ ke,
    float ca, float cb, float cc2, float cd, float ce,
    const short* __restrict__ Wt, const float* __restrict__ bias,
    const float* __restrict__ Et,
    u16* __restrict__ out,
    const float* __restrict__ st, float cfrac)
{
    if (st[3] != 0.0f) return;
    __shared__ __align__(16) char lds[180*256];
    const int b    = blockIdx.y;
    const int tile = blockIdx.x;
    const int ty   = (tile >> 2) * 16;
    const int tx   = (tile & 3) * 8;
    const int tid  = threadIdx.x;
    const float dt = st[2];

    const size_t ibase = (size_t)b * 131072;
    for (int i = tid; i < 180*16; i += 256) {
        const int pos = i >> 4, cc = i & 15;
        const int sy = pos / 10, sx = pos - sy*10;
        const int gy = ty + sy - 1, gx = tx + sx - 1;
        const bool ok = ((unsigned)gy < 32u) && ((unsigned)gx < 32u);
        uint4 w128;
        if (!ok) {
            w128 = make_uint4(0u, 0u, 0u, 0u);
        } else if (NK < 0) {
            w128 = *(const uint4*)(bfin + ibase + (size_t)(gy*32 + gx)*128 + cc*8);
        } else {
            const size_t idx = ibase + (size_t)(gy*32 + gx)*128 + cc*8;
            float v[8];
            *(float4*)(v)     = *(const float4*)(basef + idx);
            *(float4*)(v + 4) = *(const float4*)(basef + idx + 4);
            if (NK >= 1) fma8(v, ka + idx, dt*ca);
            if (NK >= 2) fma8(v, kb + idx, dt*cb);
            if (NK >= 3) fma8(v, kc + idx, dt*cc2);
            if (NK >= 4) fma8(v, kd + idx, dt*cd);
            if (NK >= 5) fma8(v, ke + idx, dt*ce);
            w128 = pk8(v);
        }
        *(uint4*)(lds + pos*256 + ((cc*16) ^ ((pos & 7) << 4))) = w128;
    }
    __syncthreads();

    const int l  = tid & 63;
    const int w  = tid >> 6;
    const int wy = w >> 1, wx = w & 1;
    const int lr = l & 15,  kg = l >> 4;

    float4v acc[4][4];
    #pragma unroll
    for (int ra = 0; ra < 4; ++ra)
        #pragma unroll
        for (int nb = 0; nb < 4; ++nb)
            acc[ra][nb] = (float4v){0.f, 0.f, 0.f, 0.f};

    int sy0[4], sx0[4];
    #pragma unroll
    for (int ra = 0; ra < 4; ++ra) {
        const int r = wy*64 + ra*16 + lr;
        sy0[ra] = r >> 3; sx0[ra] = r & 7;
    }

    #pragma unroll
    for (int ky = 0; ky < 3; ++ky) {
        #pragma unroll
        for (int kx = 0; kx < 3; ++kx) {
            const int tap = ky*3 + kx;
            #pragma unroll
            for (int kk = 0; kk < 4; ++kk) {
                short8v a[4], bb[4];
                const int cc = kk*4 + kg;
                #pragma unroll
                for (int ra = 0; ra < 4; ++ra) {
                    const int pos = (sy0[ra] + ky)*10 + sx0[ra] + kx;
                    a[ra] = *(const short8v*)(lds + pos*256 + ((cc*16) ^ ((pos & 7) << 4)));
                }
                const short* wb = Wt + tap*128 + kk*32 + kg*8;
                #pragma unroll
                for (int nb = 0; nb < 4; ++nb) {
                    const int cout = wx*64 + nb*16 + lr;
                    bb[nb] = *(const short8v*)(wb + (size_t)cout*KDIM);
                }
                #pragma unroll
                for (int ra = 0; ra < 4; ++ra)
                    #pragma unroll
                    for (int nb = 0; nb < 4; ++nb)
                        acc[ra][nb] = __builtin_amdgcn_mfma_f32_16x16x32_bf16(a[ra], bb[nb], acc[ra][nb], 0, 0, 0);
            }
        }
    }

    const float tval = st[0] + cfrac*dt;
    #pragma unroll
    for (int nb = 0; nb < 4; ++nb) {
        const int cout = wx*64 + nb*16 + lr;
        const float bsv = bias[cout];
        #pragma unroll
        for (int ra = 0; ra < 4; ++ra) {
            #pragma unroll
            for (int ri = 0; ri < 4; ++ri) {
                const int r  = wy*64 + ra*16 + kg*4 + ri;
                const int yy = ty + (r >> 3), xx = tx + (r & 7);
                const int cy = (yy == 0) ? 0 : ((yy == 31) ? 2 : 1);
                const int cx = (xx == 0) ? 0 : ((xx == 31) ? 2 : 1);
                float v = acc[ra][nb][ri] + bsv + tval*Et[(cy*3 + cx)*128 + cout];
                v = fmaxf(v, 0.f);
                out[(size_t)b*131072 + (size_t)(yy*32 + xx)*128 + cout] = f2b(v);
            }
        }
    }
}

__global__ __launch_bounds__(256) void axpy5_kernel(
    float* __restrict__ y5, const float* __restrict__ y,
    const u16* __restrict__ k1, const u16* __restrict__ k3,
    const u16* __restrict__ k4, const u16* __restrict__ k5,
    const u16* __restrict__ k6,
    float c1, float c3, float c4, float c5, float c6,
    const float* __restrict__ st)
{
    if (st[3] != 0.0f) return;
    const float dt = st[2];
    int stride = gridDim.x * blockDim.x;
    for (int i = blockIdx.x*blockDim.x + threadIdx.x; i < N8; i += stride) {
        const size_t base = (size_t)i * 8;
        float v[8];
        *(float4*)(v)     = *(const float4*)(y + base);
        *(float4*)(v + 4) = *(const float4*)(y + base + 4);
        fma8(v, k1 + base, dt*c1);
        fma8(v, k3 + base, dt*c3);
        fma8(v, k4 + base, dt*c4);
        fma8(v, k5 + base, dt*c5);
        fma8(v, k6 + base, dt*c6);
        *(float4*)(y5 + base)     = *(const float4*)(v);
        *(float4*)(y5 + base + 4) = *(const float4*)(v + 4);
    }
}

__global__ __launch_bounds__(256) void err_reduce_kernel(
    const float* __restrict__ y,  const float* __restrict__ y5,
    const u16* __restrict__ k1, const u16* __restrict__ k3,
    const u16* __restrict__ k4, const u16* __restrict__ k5,
    const u16* __restrict__ k6, const u16* __restrict__ k7,
    const float* __restrict__ st, double* __restrict__ acc_slot)
{
    if (st[3] != 0.0f) return;
    const float dt = st[2];
    const float ER1 = (float)(35.0/384.0 - 5179.0/57600.0);
    const float ER3 = (float)(500.0/1113.0 - 7571.0/16695.0);
    const float ER4 = (float)(125.0/192.0 - 393.0/640.0);
    const float ER5 = (float)(-2187.0/6784.0 + 92097.0/339200.0);
    const float ER6 = (float)(11.0/84.0 - 187.0/2100.0);
    const float ER7 = (float)(-1.0/40.0);
    float lsum = 0.f;
    int stride = gridDim.x*blockDim.x;
    for (int i = blockIdx.x*blockDim.x + threadIdx.x; i < N8; i += stride) {
        const size_t base = (size_t)i * 8;
        float a[8], c[8], d[8], e[8], f[8], g[8], yv[8], v5[8];
        ld8(k1 + base, a); ld8(k3 + base, c); ld8(k4 + base, d);
        ld8(k5 + base, e); ld8(k6 + base, f); ld8(k7 + base, g);
        *(float4*)(yv)     = *(const float4*)(y + base);
        *(float4*)(yv + 4) = *(const float4*)(y + base + 4);
        *(float4*)(v5)     = *(const float4*)(y5 + base);
        *(float4*)(v5 + 4) = *(const float4*)(y5 + base + 4);
        #pragma unroll
        for (int j = 0; j < 8; ++j) {
            float err = dt*(ER1*a[j] + ER3*c[j] + ER4*d[j] + ER5*e[j] + ER6*f[j] + ER7*g[j]);
            float sc  = 1e-3f + 1e-3f*fmaxf(fabsf(yv[j]), fabsf(v5[j]));
            float rr = err/sc; lsum += rr*rr;
        }
    }
    #pragma unroll
    for (int off = 32; off > 0; off >>= 1) lsum += __shfl_down(lsum, off, 64);
    __shared__ float ws_[4];
    int wid = threadIdx.x >> 6, lane = threadIdx.x & 63;
    if (lane == 0) ws_[wid] = lsum;
    __syncthreads();
    if (threadIdx.x == 0) {
        float bs = ws_[0] + ws_[1] + ws_[2] + ws_[3];
        atomicAdd(acc_slot, (double)bs);
    }
}

__global__ __launch_bounds__(64) void ctrl_kernel(float* __restrict__ st, const double* __restrict__ acc_slot)
{
    if (threadIdx.x != 0) return;
    ctrl_body(st, *acc_slot);
}

// ================================ host =====================================

extern "C" void kernel_launch(void* const* d_in, const int* in_sizes, int n_in,
                              void* d_out, int out_size, void* d_ws, size_t ws_size,
                              hipStream_t stream)
{
    const float* xp  = (const float*)d_in[0];
    const float* w1p = (const float*)d_in[1];
    const float* b1p = (const float*)d_in[2];
    const float* w2p = (const float*)d_in[3];
    const float* b2p = (const float*)d_in[4];
    char*  wsp  = (char*)d_ws;
    float* outp = (float*)d_out;

    void* kargs[7];
    kargs[0] = (void*)&xp;
    kargs[1] = (void*)&w1p;
    kargs[2] = (void*)&b1p;
    kargs[3] = (void*)&w2p;
    kargs[4] = (void*)&b2p;
    kargs[5] = (void*)&wsp;
    kargs[6] = (void*)&outp;

    hipError_t rc = hipLaunchCooperativeKernel((const void*)ode_persist,
                                               dim3(GRID), dim3(BLK),
                                               kargs, 0, stream);
    if (rc == hipSuccess) {
        (void)in_sizes; (void)n_in; (void)out_size; (void)ws_size;
        return;
    }
    (void)hipGetLastError();   // clear sticky error, fall back to multi-kernel path

    double* acc = (double*)wsp;
    float*  st  = (float*)(wsp + 256);
    float*  E1t = (float*)(wsp + 512);
    float*  E2t = (float*)(wsp + 5120);
    short*  Wt1 = (short*)(wsp + 10240);
    short*  Wt2 = (short*)(wsp + 305152);
    char*   bufs = wsp + 1048576;
    float* y  = (float*)(bufs);
    float* y5 = (float*)(bufs + (size_t)NTOT*4);
    u16* k1 = (u16*)(bufs + (size_t)NTOT*8);
    u16* k2 = (u16*)(bufs + (size_t)NTOT*10);
    u16* k3 = (u16*)(bufs + (size_t)NTOT*12);
    u16* k4 = (u16*)(bufs + (size_t)NTOT*14);
    u16* k5 = (u16*)(bufs + (size_t)NTOT*16);
    u16* k6 = (u16*)(bufs + (size_t)NTOT*18);
    u16* k7 = (u16*)(bufs + (size_t)NTOT*20);
    u16* h  = (u16*)(bufs + (size_t)NTOT*22);

    const dim3 cgrid(8, 32);
    const dim3 cblk(256);
    const int ab = 2048;

    init_kernel<<<1, 64, 0, stream>>>(st, acc);
    prep_kernel<<<10, 256, 0, stream>>>(w1p, Wt1, E1t);
    prep_kernel<<<10, 256, 0, stream>>>(w2p, Wt2, E2t);
    copy_kernel<<<ab, 256, 0, stream>>>(y, xp);

    for (int it = 0; it < 32; ++it) {
        conv_mfma<0><<<cgrid, cblk, 0, stream>>>(y, h, k1,k1,k1,k1,k1, 0,0,0,0,0, Wt1, b1p, E1t, h,  st, 0.0f);
        conv_mfma<-1><<<cgrid, cblk, 0, stream>>>(y, h, k1,k1,k1,k1,k1, 0,0,0,0,0, Wt2, b2p, E2t, k1, st, 0.0f);
        conv_mfma<1><<<cgrid, cblk, 0, stream>>>(y, h, k1,k1,k1,k1,k1, A21,0,0,0,0, Wt1, b1p, E1t, h,  st, CF2);
        conv_mfma<-1><<<cgrid, cblk, 0, stream>>>(y, h, k1,k1,k1,k1,k1, 0,0,0,0,0, Wt2, b2p, E2t, k2, st, CF2);
        conv_mfma<2><<<cgrid, cblk, 0, stream>>>(y, h, k1,k2,k1,k1,k1, A31,A32,0,0,0, Wt1, b1p, E1t, h,  st, CF3);
        conv_mfma<-1><<<cgrid, cblk, 0, stream>>>(y, h, k1,k1,k1,k1,k1, 0,0,0,0,0, Wt2, b2p, E2t, k3, st, CF3);
        conv_mfma<3><<<cgrid, cblk, 0, stream>>>(y, h, k1,k2,k3,k1,k1, A41,A42,A43,0,0, Wt1, b1p, E1t, h,  st, CF4);
        conv_mfma<-1><<<cgrid, cblk, 0, stream>>>(y, h, k1,k1,k1,k1,k1, 0,0,0,0,0, Wt2, b2p, E2t, k4, st, CF4);
        conv_mfma<4><<<cgrid, cblk, 0, stream>>>(y, h, k1,k2,k3,k4,k1, A51,A52,A53,A54,0, Wt1, b1p, E1t, h,  st, CF5);
        conv_mfma<-1><<<cgrid, cblk, 0, stream>>>(y, h, k1,k1,k1,k1,k1, 0,0,0,0,0, Wt2, b2p, E2t, k5, st, CF5);
        conv_mfma<5><<<cgrid, cblk, 0, stream>>>(y, h, k1,k2,k3,k4,k5, A61,A62,A63,A64,A65, Wt1, b1p, E1t, h,  st, 1.0f);
        conv_mfma<-1><<<cgrid, cblk, 0, stream>>>(y, h, k1,k1,k1,k1,k1, 0,0,0,0,0, Wt2, b2p, E2t, k6, st, 1.0f);
        axpy5_kernel<<<ab, 256, 0, stream>>>(y5, y, k1, k3, k4, k5, k6, B1c, B3c, B4c, B5c, B6c, st);
        conv_mfma<0><<<cgrid, cblk, 0, stream>>>(y5, h, k1,k1,k1,k1,k1, 0,0,0,0,0, Wt1, b1p, E1t, h,  st, 1.0f);
        conv_mfma<-1><<<cgrid, cblk, 0, stream>>>(y5, h, k1,k1,k1,k1,k1, 0,0,0,0,0, Wt2, b2p, E2t, k7, st, 1.0f);
        err_reduce_kernel<<<ab, 256, 0, stream>>>(y, y5, k1, k3, k4, k5, k6, k7, st, acc + it);
        ctrl_kernel<<<1, 64, 0, stream>>>(st, acc + it);
        copy_if_adv_kernel<<<ab, 256, 0, stream>>>(y, y5, st);
    }

    copy_kernel<<<ab, 256, 0, stream>>>(outp, y);

    (void)in_sizes; (void)n_in; (void)out_size; (void)ws_size;
}

// Round 7
// 4604.195 us; speedup vs baseline: 1.6637x; 1.6637x over previous
//
#include <hip/hip_runtime.h>
#include <math.h>

#define NTOT  4194304      // 32*32*32*128
#define N4    1048576
#define N8    524288
#define KDIM  1152         // 9 taps * 128 cin
#define EGRID 512          // err/ctrl grid

typedef unsigned short u16;
typedef __attribute__((ext_vector_type(8))) short short8v;   // 8 bf16
typedef __attribute__((ext_vector_type(4))) float float4v;   // MFMA acc

__device__ inline float b2f(u16 u) { union { unsigned int i; float f; } x; x.i = ((unsigned int)u) << 16; return x.f; }
__device__ inline u16   f2b(float f) {
    union { unsigned int i; float f; } x; x.f = f;
    unsigned int u = x.i;
    return (u16)((u + 0x7fffu + ((u >> 16) & 1u)) >> 16);   // RNE
}
__device__ inline void ld8(const u16* __restrict__ p, float* v) {
    uint4 r = *(const uint4*)p;
    v[0] = b2f((u16)(r.x & 0xffff)); v[1] = b2f((u16)(r.x >> 16));
    v[2] = b2f((u16)(r.y & 0xffff)); v[3] = b2f((u16)(r.y >> 16));
    v[4] = b2f((u16)(r.z & 0xffff)); v[5] = b2f((u16)(r.z >> 16));
    v[6] = b2f((u16)(r.w & 0xffff)); v[7] = b2f((u16)(r.w >> 16));
}
__device__ inline uint4 pk8(const float* v) {
    uint4 o;
    o.x = (unsigned int)f2b(v[0]) | ((unsigned int)f2b(v[1]) << 16);
    o.y = (unsigned int)f2b(v[2]) | ((unsigned int)f2b(v[3]) << 16);
    o.z = (unsigned int)f2b(v[4]) | ((unsigned int)f2b(v[5]) << 16);
    o.w = (unsigned int)f2b(v[6]) | ((unsigned int)f2b(v[7]) << 16);
    return o;
}
__device__ inline void fma8(float* __restrict__ v, const u16* __restrict__ p, float s) {
    float kv[8];
    ld8(p, kv);
    #pragma unroll
    for (int j = 0; j < 8; ++j) v[j] = fmaf(s, kv[j], v[j]);
}

// Butcher tableau
constexpr float A21 = 0.2f;
constexpr float A31 = (float)(3.0/40.0),       A32 = (float)(9.0/40.0);
constexpr float A41 = (float)(44.0/45.0),      A42 = (float)(-56.0/15.0),      A43 = (float)(32.0/9.0);
constexpr float A51 = (float)(19372.0/6561.0), A52 = (float)(-25360.0/2187.0), A53 = (float)(64448.0/6561.0), A54 = (float)(-212.0/729.0);
constexpr float A61 = (float)(9017.0/3168.0),  A62 = (float)(-355.0/33.0),     A63 = (float)(46732.0/5247.0), A64 = (float)(49.0/176.0), A65 = (float)(-5103.0/18656.0);
constexpr float B1c = (float)(35.0/384.0),     B3c = (float)(500.0/1113.0),    B4c = (float)(125.0/192.0),    B5c = (float)(-2187.0/6784.0), B6c = (float)(11.0/84.0);
constexpr float CF2 = 0.2f, CF3 = 0.3f, CF4 = 0.8f, CF5 = (float)(8.0/9.0);

// ws scalar layout: acc double[32] @0; cnt uint[32] @256; st float[8] @512
//   st[0]=t st[1]=dt st[2]=dt_c st[3]=done st[5]=flag (0: y=yA, 1: y=yB)
// E1t @1024, E2t @5632, Wt1 @10240, Wt2 @305152, tensor bufs @1 MiB.

__global__ __launch_bounds__(64) void init_kernel(float* __restrict__ st,
                                                  double* __restrict__ acc,
                                                  unsigned* __restrict__ cnt)
{
    int i = threadIdx.x;
    if (i < 32) { acc[i] = 0.0; cnt[i] = 0u; }
    if (i == 0) { st[0]=0.0f; st[1]=0.05f; st[2]=0.05f; st[3]=0.0f; st[4]=0.0f; st[5]=0.0f; }
}

__global__ __launch_bounds__(256) void prep_kernel(
    const float* __restrict__ w, short* __restrict__ Wt, float* __restrict__ Et)
{
    const int part = blockIdx.x;
    const int tid = threadIdx.x;
    if (part < 9) {
        const int tap = part;
        for (int i = tid; i < 128*128; i += 256) {
            const int ci = i >> 7, co = i & 127;
            Wt[co*KDIM + tap*128 + ci] = (short)f2b(w[(tap*129 + ci)*128 + co]);
        }
    } else {
        for (int i = tid; i < 9*128; i += 256) {
            const int cls = i >> 7, co = i & 127;
            const int cy = cls / 3, cx = cls % 3;
            float s = 0.f;
            for (int ky = 0; ky < 3; ++ky) {
                if ((cy==0 && ky==0) || (cy==2 && ky==2)) continue;
                for (int kx = 0; kx < 3; ++kx) {
                    if ((cx==0 && kx==0) || (cx==2 && kx==2)) continue;
                    s += w[((ky*3+kx)*129 + 128)*128 + co];
                }
            }
            Et[cls*128 + co] = s;
        }
    }
}

__global__ __launch_bounds__(256) void copy_in_kernel(float* __restrict__ dst, const float* __restrict__ src)
{
    int stride = gridDim.x * blockDim.x;
    for (int i = blockIdx.x*blockDim.x + threadIdx.x; i < N4; i += stride)
        reinterpret_cast<float4*>(dst)[i] = reinterpret_cast<const float4*>(src)[i];
}

__global__ __launch_bounds__(256) void copy_out_kernel(float* __restrict__ dst,
                                                       const float* __restrict__ yA,
                                                       const float* __restrict__ yB,
                                                       const float* __restrict__ st)
{
    const float* y = (st[5] != 0.0f) ? yB : yA;
    int stride = gridDim.x * blockDim.x;
    for (int i = blockIdx.x*blockDim.x + threadIdx.x; i < N4; i += stride)
        reinterpret_cast<float4*>(dst)[i] = reinterpret_cast<const float4*>(y)[i];
}

// ---------------------------------------------------------------------------
// Fused f-eval: u = y + dt*sum(c_j k_j) staged to LDS (12x12 halo, bf16,
// XOR-swizzled) -> conv1 into LDS h (10x10) -> conv2 -> kout (inner 8x8).
// 256 threads = 4 waves. y selected by ping-pong flag st[5]; STY5 also
// persists u (=y5) f32 into the non-current buffer.
// ---------------------------------------------------------------------------
template<int NK, bool STY5>
__global__ __launch_bounds__(256) void feval_kernel(
    const float* __restrict__ yAp, float* __restrict__ yBp,
    const u16* __restrict__ ka, const u16* __restrict__ kb,
    const u16* __restrict__ kc, const u16* __restrict__ kd,
    const u16* __restrict__ ke,
    float ca, float cb, float cc, float cd, float ce,
    const short* __restrict__ Wt1, const float* __restrict__ b1g, const float* __restrict__ E1g,
    const short* __restrict__ Wt2, const float* __restrict__ b2g, const float* __restrict__ E2g,
    u16* __restrict__ kout,
    const float* __restrict__ st, float cfrac)
{
    if (st[3] != 0.0f) return;
    __shared__ __align__(16) char ldsA[144*256];   // 36864 B
    __shared__ __align__(16) char ldsH[100*256];   // 25600 B

    const int flag = (st[5] != 0.0f);
    const float* yb  = flag ? (const float*)yBp : yAp;
    float*       y5b = flag ? (float*)yAp : yBp;

    const int img  = blockIdx.y;
    const int tile = blockIdx.x;               // 0..15
    const int ty   = ((tile >> 2) & 3) * 8;
    const int tx   = (tile & 3) * 8;
    const int tid  = threadIdx.x;
    const float dt   = st[2];
    const float tval = st[0] + cfrac * dt;
    const size_t ibase = (size_t)img * 131072;

    // ---- staging: 144 pos x 16 ch-groups ----
    {
        const float s1 = dt*ca, s2 = dt*cb, s3 = dt*cc, s4 = dt*cd, s5 = dt*ce;
        for (int i = tid; i < 144*16; i += 256) {
            const int pos = i >> 4, ch8 = i & 15;
            const int iy = pos / 12, ix = pos - iy*12;
            const int gy = ty + iy - 2, gx = tx + ix - 2;
            uint4 w128 = make_uint4(0u, 0u, 0u, 0u);
            if ((unsigned)gy < 32u && (unsigned)gx < 32u) {
                const size_t idx = ibase + (size_t)((gy << 5) + gx)*128 + ch8*8;
                float v[8];
                *(float4*)(v)     = *(const float4*)(yb + idx);
                *(float4*)(v + 4) = *(const float4*)(yb + idx + 4);
                if (NK >= 1) fma8(v, ka + idx, s1);
                if (NK >= 2) fma8(v, kb + idx, s2);
                if (NK >= 3) fma8(v, kc + idx, s3);
                if (NK >= 4) fma8(v, kd + idx, s4);
                if (NK >= 5) fma8(v, ke + idx, s5);
                if (STY5) {
                    if ((unsigned)(iy - 2) < 8u && (unsigned)(ix - 2) < 8u) {
                        *(float4*)(y5b + idx)     = *(const float4*)(v);
                        *(float4*)(y5b + idx + 4) = *(const float4*)(v + 4);
                    }
                }
                w128 = pk8(v);
            }
            *(uint4*)(ldsA + pos*256 + ((ch8*16) ^ ((pos & 7) << 4))) = w128;
        }
    }
    __syncthreads();

    const int l  = tid & 63, w = tid >> 6;     // 4 waves
    const int lr = l & 15,  kg = l >> 4;

    // ---- conv1: M=128-pad (10x10 h positions), N=128; 2 M-frags x 8 N-frags/wave ----
    {
        float4v acc[2][8];
        #pragma unroll
        for (int j = 0; j < 2; ++j)
            #pragma unroll
            for (int cf = 0; cf < 8; ++cf) acc[j][cf] = (float4v){0.f, 0.f, 0.f, 0.f};
        int py[2], px[2];
        #pragma unroll
        for (int j = 0; j < 2; ++j) {
            const int p = (w*2 + j)*16 + lr;
            py[j] = p / 10; px[j] = p - py[j]*10;
        }
        #pragma unroll 1
        for (int ky = 0; ky < 3; ++ky) {
            #pragma unroll 1
            for (int kx = 0; kx < 3; ++kx) {
                const int tap = ky*3 + kx;
                #pragma unroll
                for (int kk = 0; kk < 4; ++kk) {
                    short8v a[2], bb[8];
                    #pragma unroll
                    for (int j = 0; j < 2; ++j) {
                        int pp = (py[j] + ky)*12 + px[j] + kx;
                        pp = (pp < 144) ? pp : 143;
                        a[j] = *(const short8v*)(ldsA + pp*256 + ((16*(kk*4 + kg)) ^ ((pp & 7) << 4)));
                    }
                    const short* wb = Wt1 + tap*128 + kk*32 + kg*8;
                    #pragma unroll
                    for (int cf = 0; cf < 8; ++cf)
                        bb[cf] = *(const short8v*)(wb + (size_t)(cf*16 + lr)*KDIM);
                    #pragma unroll
                    for (int j = 0; j < 2; ++j)
                        #pragma unroll
                        for (int cf = 0; cf < 8; ++cf)
                            acc[j][cf] = __builtin_amdgcn_mfma_f32_16x16x32_bf16(a[j], bb[cf], acc[j][cf], 0, 0, 0);
                }
            }
        }
        // epilogue -> ldsH (zero outside image, skip pad rows >= 100)
        #pragma unroll
        for (int j = 0; j < 2; ++j)
            #pragma unroll
            for (int ri = 0; ri < 4; ++ri) {
                const int p = (w*2 + j)*16 + kg*4 + ri;
                if (p < 100) {
                    const int hy = p / 10, hx = p - (p/10)*10;
                    const int gy = ty + hy - 1, gx = tx + hx - 1;
                    const bool in = ((unsigned)gy < 32u) && ((unsigned)gx < 32u);
                    const int cy = (gy == 0) ? 0 : ((gy == 31) ? 2 : 1);
                    const int cx = (gx == 0) ? 0 : ((gx == 31) ? 2 : 1);
                    const int ecl = (cy*3 + cx)*128;
                    #pragma unroll
                    for (int cf = 0; cf < 8; ++cf) {
                        const int c = cf*16 + lr;
                        float v = 0.f;
                        if (in) v = fmaxf(acc[j][cf][ri] + b1g[c] + tval*E1g[ecl + c], 0.f);
                        *(u16*)(ldsH + p*256 + ((2*c) ^ ((p & 7) << 4))) = f2b(v);
                    }
                }
            }
    }
    __syncthreads();

    // ---- conv2: M=64 (inner 8x8), N=128; 1 M-frag x 8 N-frags/wave ----
    {
        float4v acc[8];
        #pragma unroll
        for (int cf = 0; cf < 8; ++cf) acc[cf] = (float4v){0.f, 0.f, 0.f, 0.f};
        const int r = w*16 + lr;
        const int oy = r >> 3, ox = r & 7;
        #pragma unroll 1
        for (int ky = 0; ky < 3; ++ky) {
            #pragma unroll 1
            for (int kx = 0; kx < 3; ++kx) {
                const int tap = ky*3 + kx;
                #pragma unroll
                for (int kk = 0; kk < 4; ++kk) {
                    const int p = (oy + ky)*10 + ox + kx;
                    short8v a = *(const short8v*)(ldsH + p*256 + ((16*(kk*4 + kg)) ^ ((p & 7) << 4)));
                    const short* wb = Wt2 + tap*128 + kk*32 + kg*8;
                    short8v bb[8];
                    #pragma unroll
                    for (int cf = 0; cf < 8; ++cf)
                        bb[cf] = *(const short8v*)(wb + (size_t)(cf*16 + lr)*KDIM);
                    #pragma unroll
                    for (int cf = 0; cf < 8; ++cf)
                        acc[cf] = __builtin_amdgcn_mfma_f32_16x16x32_bf16(a, bb[cf], acc[cf], 0, 0, 0);
                }
            }
        }
        #pragma unroll
        for (int ri = 0; ri < 4; ++ri) {
            const int r2  = w*16 + kg*4 + ri;
            const int gy  = ty + (r2 >> 3), gx = tx + (r2 & 7);
            const int cy  = (gy == 0) ? 0 : ((gy == 31) ? 2 : 1);
            const int cx  = (gx == 0) ? 0 : ((gx == 31) ? 2 : 1);
            const int ecl = (cy*3 + cx)*128;
            const size_t obase = ibase + (size_t)((gy << 5) + gx)*128;
            #pragma unroll
            for (int cf = 0; cf < 8; ++cf) {
                const int c = cf*16 + lr;
                float v = fmaxf(acc[cf][ri] + b2g[c] + tval*E2g[ecl + c], 0.f);
                kout[obase + c] = f2b(v);
            }
        }
    }
}

// ---------------------------------------------------------------------------
// Fused error-norm reduction + controller (last-block-done pattern).
// ---------------------------------------------------------------------------
__global__ __launch_bounds__(256) void err_ctrl_kernel(
    const float* __restrict__ yAp, const float* __restrict__ yBp,
    const u16* __restrict__ k1, const u16* __restrict__ k3,
    const u16* __restrict__ k4, const u16* __restrict__ k5,
    const u16* __restrict__ k6, const u16* __restrict__ k7,
    float* __restrict__ st, double* __restrict__ acc, unsigned* __restrict__ cnt,
    int it)
{
    if (st[3] != 0.0f) return;
    const int flag = (st[5] != 0.0f);
    const float* y  = flag ? yBp : yAp;
    const float* y5 = flag ? yAp : yBp;
    const float dt = st[2];
    const float ER1 = (float)(35.0/384.0 - 5179.0/57600.0);
    const float ER3 = (float)(500.0/1113.0 - 7571.0/16695.0);
    const float ER4 = (float)(125.0/192.0 - 393.0/640.0);
    const float ER5 = (float)(-2187.0/6784.0 + 92097.0/339200.0);
    const float ER6 = (float)(11.0/84.0 - 187.0/2100.0);
    const float ER7 = (float)(-1.0/40.0);
    float lsum = 0.f;
    const int stride = gridDim.x * blockDim.x;
    for (int i = blockIdx.x*blockDim.x + threadIdx.x; i < N8; i += stride) {
        const size_t base = (size_t)i * 8;
        float a[8], c[8], d[8], e[8], f[8], g[8], yv[8], v5[8];
        ld8(k1 + base, a); ld8(k3 + base, c); ld8(k4 + base, d);
        ld8(k5 + base, e); ld8(k6 + base, f); ld8(k7 + base, g);
        *(float4*)(yv)     = *(const float4*)(y + base);
        *(float4*)(yv + 4) = *(const float4*)(y + base + 4);
        *(float4*)(v5)     = *(const float4*)(y5 + base);
        *(float4*)(v5 + 4) = *(const float4*)(y5 + base + 4);
        #pragma unroll
        for (int j = 0; j < 8; ++j) {
            float err = dt*(ER1*a[j] + ER3*c[j] + ER4*d[j] + ER5*e[j] + ER6*f[j] + ER7*g[j]);
            float sc  = 1e-3f + 1e-3f*fmaxf(fabsf(yv[j]), fabsf(v5[j]));
            float rr = err/sc; lsum += rr*rr;
        }
    }
    #pragma unroll
    for (int off = 32; off > 0; off >>= 1) lsum += __shfl_down(lsum, off, 64);
    __shared__ float ws_[4];
    const int wid = threadIdx.x >> 6, lane = threadIdx.x & 63;
    if (lane == 0) ws_[wid] = lsum;
    __syncthreads();
    if (threadIdx.x == 0) {
        const float bs = ws_[0] + ws_[1] + ws_[2] + ws_[3];
        atomicAdd(acc + it, (double)bs);
        __threadfence();
        const unsigned v = atomicAdd(cnt + it, 1u);
        if (v == (unsigned)(EGRID - 1)) {
            __threadfence();
            const double a = atomicAdd(acc + it, 0.0);   // coherent read
            float t = st[0], dtp = st[1], dtc = st[2];
            float en = sqrtf((float)(a / (double)NTOT));
            en = fmaxf(en, 1e-10f);
            const bool accept = (en <= 1.0f);
            float factor = fminf(fmaxf(0.9f * powf(en, -0.2f), 0.2f), 10.0f);
            const bool adv = accept;                     // done is false here
            if (adv) t += dtc;
            dtp = dtc * factor;
            const bool done = (t >= 1.0f - 1e-6f);
            st[0] = t; st[1] = dtp;
            st[2] = fminf(dtp, 1.0f - t);
            st[3] = done ? 1.0f : 0.0f;
            st[4] = adv ? 1.0f : 0.0f;
            if (adv) st[5] = flag ? 0.0f : 1.0f;         // ping-pong flip
        }
    }
}

// ================================ host =====================================

extern "C" void kernel_launch(void* const* d_in, const int* in_sizes, int n_in,
                              void* d_out, int out_size, void* d_ws, size_t ws_size,
                              hipStream_t stream)
{
    const float* xp  = (const float*)d_in[0];
    const float* w1p = (const float*)d_in[1];
    const float* b1p = (const float*)d_in[2];
    const float* w2p = (const float*)d_in[3];
    const float* b2p = (const float*)d_in[4];
    char*  wsp  = (char*)d_ws;
    float* outp = (float*)d_out;

    double*   acc = (double*)wsp;                  // [32] @0
    unsigned* cnt = (unsigned*)(wsp + 256);        // [32] @256
    float*    st  = (float*)(wsp + 512);           // [8]  @512
    float*    E1t = (float*)(wsp + 1024);          // 9*128 f32
    float*    E2t = (float*)(wsp + 5632);
    short*    Wt1 = (short*)(wsp + 10240);         // 128*1152 bf16
    short*    Wt2 = (short*)(wsp + 305152);
    char*     bufs = wsp + 1048576;
    float* yA = (float*)(bufs);                    // 16 MiB
    float* yB = (float*)(bufs + (size_t)NTOT*4);   // 16 MiB
    u16* k1 = (u16*)(bufs + (size_t)NTOT*8);
    u16* k2 = (u16*)(bufs + (size_t)NTOT*10);
    u16* k3 = (u16*)(bufs + (size_t)NTOT*12);
    u16* k4 = (u16*)(bufs + (size_t)NTOT*14);
    u16* k5 = (u16*)(bufs + (size_t)NTOT*16);
    u16* k6 = (u16*)(bufs + (size_t)NTOT*18);
    u16* k7 = (u16*)(bufs + (size_t)NTOT*20);

    const dim3 fgrid(16, 32);    // 16 tiles (4y x 4x of 8x8) x 32 images
    const dim3 fblk(256);

    init_kernel<<<1, 64, 0, stream>>>(st, acc, cnt);
    prep_kernel<<<10, 256, 0, stream>>>(w1p, Wt1, E1t);
    prep_kernel<<<10, 256, 0, stream>>>(w2p, Wt2, E2t);
    copy_in_kernel<<<2048, 256, 0, stream>>>(yA, xp);

    for (int it = 0; it < 32; ++it) {
        feval_kernel<0,false><<<fgrid, fblk, 0, stream>>>(yA, yB, k1,k1,k1,k1,k1, 0,0,0,0,0,
            Wt1,b1p,E1t, Wt2,b2p,E2t, k1, st, 0.0f);
        feval_kernel<1,false><<<fgrid, fblk, 0, stream>>>(yA, yB, k1,k1,k1,k1,k1, A21,0,0,0,0,
            Wt1,b1p,E1t, Wt2,b2p,E2t, k2, st, CF2);
        feval_kernel<2,false><<<fgrid, fblk, 0, stream>>>(yA, yB, k1,k2,k2,k2,k2, A31,A32,0,0,0,
            Wt1,b1p,E1t, Wt2,b2p,E2t, k3, st, CF3);
        feval_kernel<3,false><<<fgrid, fblk, 0, stream>>>(yA, yB, k1,k2,k3,k3,k3, A41,A42,A43,0,0,
            Wt1,b1p,E1t, Wt2,b2p,E2t, k4, st, CF4);
        feval_kernel<4,false><<<fgrid, fblk, 0, stream>>>(yA, yB, k1,k2,k3,k4,k4, A51,A52,A53,A54,0,
            Wt1,b1p,E1t, Wt2,b2p,E2t, k5, st, CF5);
        feval_kernel<5,false><<<fgrid, fblk, 0, stream>>>(yA, yB, k1,k2,k3,k4,k5, A61,A62,A63,A64,A65,
            Wt1,b1p,E1t, Wt2,b2p,E2t, k6, st, 1.0f);
        feval_kernel<5,true><<<fgrid, fblk, 0, stream>>>(yA, yB, k1,k3,k4,k5,k6, B1c,B3c,B4c,B5c,B6c,
            Wt1,b1p,E1t, Wt2,b2p,E2t, k7, st, 1.0f);
        err_ctrl_kernel<<<EGRID, 256, 0, stream>>>(yA, yB, k1, k3, k4, k5, k6, k7,
            st, acc, cnt, it);
    }

    copy_out_kernel<<<2048, 256, 0, stream>>>(outp, yA, yB, st);

    (void)in_sizes; (void)n_in; (void)out_size; (void)ws_size;
}

// Round 8
// 3000.640 us; speedup vs baseline: 2.5528x; 1.5344x over previous
//
#include <hip/hip_runtime.h>
#include <math.h>

#define NTOT  4194304      // 32*32*32*128
#define N4    1048576
#define N8    524288
#define KDIM  1152         // 9 taps * 128 cin
#define EGRID 512
#define MAXIT 24

typedef unsigned short u16;
typedef __attribute__((ext_vector_type(8))) short short8v;   // 8 bf16
typedef __attribute__((ext_vector_type(4))) float float4v;   // MFMA acc

__device__ inline float b2f(u16 u) { union { unsigned int i; float f; } x; x.i = ((unsigned int)u) << 16; return x.f; }
__device__ inline u16   f2b(float f) {
    union { unsigned int i; float f; } x; x.f = f;
    unsigned int u = x.i;
    return (u16)((u + 0x7fffu + ((u >> 16) & 1u)) >> 16);   // RNE
}
__device__ inline void ld8(const u16* __restrict__ p, float* v) {
    uint4 r = *(const uint4*)p;
    v[0] = b2f((u16)(r.x & 0xffff)); v[1] = b2f((u16)(r.x >> 16));
    v[2] = b2f((u16)(r.y & 0xffff)); v[3] = b2f((u16)(r.y >> 16));
    v[4] = b2f((u16)(r.z & 0xffff)); v[5] = b2f((u16)(r.z >> 16));
    v[6] = b2f((u16)(r.w & 0xffff)); v[7] = b2f((u16)(r.w >> 16));
}
__device__ inline uint4 pk8(const float* v) {
    uint4 o;
    o.x = (unsigned int)f2b(v[0]) | ((unsigned int)f2b(v[1]) << 16);
    o.y = (unsigned int)f2b(v[2]) | ((unsigned int)f2b(v[3]) << 16);
    o.z = (unsigned int)f2b(v[4]) | ((unsigned int)f2b(v[5]) << 16);
    o.w = (unsigned int)f2b(v[6]) | ((unsigned int)f2b(v[7]) << 16);
    return o;
}
__device__ inline void fma8(float* __restrict__ v, const u16* __restrict__ p, float s) {
    float kv[8];
    ld8(p, kv);
    #pragma unroll
    for (int j = 0; j < 8; ++j) v[j] = fmaf(s, kv[j], v[j]);
}

// Butcher tableau
constexpr float A21 = 0.2f;
constexpr float A31 = (float)(3.0/40.0),       A32 = (float)(9.0/40.0);
constexpr float A41 = (float)(44.0/45.0),      A42 = (float)(-56.0/15.0),      A43 = (float)(32.0/9.0);
constexpr float A51 = (float)(19372.0/6561.0), A52 = (float)(-25360.0/2187.0), A53 = (float)(64448.0/6561.0), A54 = (float)(-212.0/729.0);
constexpr float A61 = (float)(9017.0/3168.0),  A62 = (float)(-355.0/33.0),     A63 = (float)(46732.0/5247.0), A64 = (float)(49.0/176.0), A65 = (float)(-5103.0/18656.0);
constexpr float B1c = (float)(35.0/384.0),     B3c = (float)(500.0/1113.0),    B4c = (float)(125.0/192.0),    B5c = (float)(-2187.0/6784.0), B6c = (float)(11.0/84.0);
constexpr float CF2 = 0.2f, CF3 = 0.3f, CF4 = 0.8f, CF5 = (float)(8.0/9.0);

// ws layout: acc double[32] @0; cnt uint[32] @256; st float[8] @512
//   st[0]=t st[1]=dt st[2]=dt_c st[3]=done st[4]=adv st[5]=flag (0:y=yA)
// E1t @1024, E2t @5632, Wt1 @10240, Wt2 @305152, tensor bufs @1 MiB.

__global__ __launch_bounds__(64) void init_kernel(float* __restrict__ st,
                                                  double* __restrict__ acc,
                                                  unsigned* __restrict__ cnt)
{
    int i = threadIdx.x;
    if (i < 32) { acc[i] = 0.0; cnt[i] = 0u; }
    if (i == 0) { st[0]=0.0f; st[1]=0.05f; st[2]=0.05f; st[3]=0.0f; st[4]=0.0f; st[5]=0.0f; }
}

__global__ __launch_bounds__(256) void prep_kernel(
    const float* __restrict__ w, short* __restrict__ Wt, float* __restrict__ Et)
{
    const int part = blockIdx.x;
    const int tid = threadIdx.x;
    if (part < 9) {
        const int tap = part;
        for (int i = tid; i < 128*128; i += 256) {
            const int ci = i >> 7, co = i & 127;
            Wt[co*KDIM + tap*128 + ci] = (short)f2b(w[(tap*129 + ci)*128 + co]);
        }
    } else {
        for (int i = tid; i < 9*128; i += 256) {
            const int cls = i >> 7, co = i & 127;
            const int cy = cls / 3, cx = cls % 3;
            float s = 0.f;
            for (int ky = 0; ky < 3; ++ky) {
                if ((cy==0 && ky==0) || (cy==2 && ky==2)) continue;
                for (int kx = 0; kx < 3; ++kx) {
                    if ((cx==0 && kx==0) || (cx==2 && kx==2)) continue;
                    s += w[((ky*3+kx)*129 + 128)*128 + co];
                }
            }
            Et[cls*128 + co] = s;
        }
    }
}

__global__ __launch_bounds__(256) void copy_in_kernel(float* __restrict__ dst, const float* __restrict__ src)
{
    int stride = gridDim.x * blockDim.x;
    for (int i = blockIdx.x*blockDim.x + threadIdx.x; i < N4; i += stride)
        reinterpret_cast<float4*>(dst)[i] = reinterpret_cast<const float4*>(src)[i];
}

__global__ __launch_bounds__(256) void copy_out_kernel(float* __restrict__ dst,
                                                       const float* __restrict__ yA,
                                                       const float* __restrict__ yB,
                                                       const float* __restrict__ st)
{
    const float* y = (st[5] != 0.0f) ? yB : yA;
    int stride = gridDim.x * blockDim.x;
    for (int i = blockIdx.x*blockDim.x + threadIdx.x; i < N4; i += stride)
        reinterpret_cast<float4*>(dst)[i] = reinterpret_cast<const float4*>(y)[i];
}

// ---------------------------------------------------------------------------
// Single conv 3x3 SAME, 128(+t)->128, bias+relu, 8x8 tile, 512 blocks.
// 4 waves in a 2M x 2N grid: each wave 2 M-frags (32 rows) x 4 N-frags
// (64 cout) -> 8 MFMA per K-step of 32.
// NK >= 0: input = flag-selected y (f32) + dt*sum(c_j k_j)  [fused axpy]
//          STY5: persist staged value (=y5) f32 to the non-current buffer.
// NK == -1: input = bfin (bf16, the h buffer).
// Output: bf16 kout (or h).
// ---------------------------------------------------------------------------
template<int NK, bool STY5>
__global__ __launch_bounds__(256) void conv_tile(
    const float* __restrict__ yAp, float* __restrict__ yBp,
    const u16* __restrict__ bfin,
    const u16* __restrict__ ka, const u16* __restrict__ kb,
    const u16* __restrict__ kc, const u16* __restrict__ kd,
    const u16* __restrict__ ke,
    float ca, float cb, float cc, float cd, float ce,
    const short* __restrict__ Wt, const float* __restrict__ bg,
    const float* __restrict__ Eg,
    u16* __restrict__ out,
    const float* __restrict__ st, float cfrac)
{
    if (st[3] != 0.0f) return;
    __shared__ __align__(16) char ldsA[100*256];   // 25600 B

    const int flag = (st[5] != 0.0f);
    const float* yb  = flag ? (const float*)yBp : yAp;
    float*       y5b = flag ? (float*)yAp : yBp;

    const int img  = blockIdx.y;
    const int tile = blockIdx.x;               // 0..15
    const int ty   = (tile >> 2) * 8;
    const int tx   = (tile & 3) * 8;
    const int tid  = threadIdx.x;
    const float dt   = st[2];
    const float tval = st[0] + cfrac * dt;
    const size_t ibase = (size_t)img * 131072;

    // ---- staging: 10x10 halo x 128 ch -> ldsA bf16 swizzled ----
    {
        const float s1 = dt*ca, s2 = dt*cb, s3 = dt*cc, s4 = dt*cd, s5 = dt*ce;
        for (int i = tid; i < 100*16; i += 256) {
            const int pos = i >> 4, ch8 = i & 15;
            const int iy = pos / 10, ix = pos - iy*10;
            const int gy = ty + iy - 1, gx = tx + ix - 1;
            uint4 w128 = make_uint4(0u, 0u, 0u, 0u);
            if ((unsigned)gy < 32u && (unsigned)gx < 32u) {
                const size_t idx = ibase + (size_t)((gy << 5) + gx)*128 + ch8*8;
                if (NK < 0) {
                    w128 = *(const uint4*)(bfin + idx);
                } else {
                    float v[8];
                    *(float4*)(v)     = *(const float4*)(yb + idx);
                    *(float4*)(v + 4) = *(const float4*)(yb + idx + 4);
                    if (NK >= 1) fma8(v, ka + idx, s1);
                    if (NK >= 2) fma8(v, kb + idx, s2);
                    if (NK >= 3) fma8(v, kc + idx, s3);
                    if (NK >= 4) fma8(v, kd + idx, s4);
                    if (NK >= 5) fma8(v, ke + idx, s5);
                    if (STY5) {
                        if ((unsigned)(iy - 1) < 8u && (unsigned)(ix - 1) < 8u) {
                            *(float4*)(y5b + idx)     = *(const float4*)(v);
                            *(float4*)(y5b + idx + 4) = *(const float4*)(v + 4);
                        }
                    }
                    w128 = pk8(v);
                }
            }
            *(uint4*)(ldsA + pos*256 + ((ch8*16) ^ ((pos & 7) << 4))) = w128;
        }
    }
    __syncthreads();

    const int l  = tid & 63, w = tid >> 6;     // 4 waves
    const int lr = l & 15,  kg = l >> 4;
    const int wy = w >> 1,  wx = w & 1;        // 2M x 2N wave grid

    float4v acc[2][4];
    #pragma unroll
    for (int mj = 0; mj < 2; ++mj)
        #pragma unroll
        for (int nf = 0; nf < 4; ++nf) acc[mj][nf] = (float4v){0.f, 0.f, 0.f, 0.f};

    int py[2], px[2];
    #pragma unroll
    for (int mj = 0; mj < 2; ++mj) {
        const int r = (wy*2 + mj)*16 + lr;     // 0..63
        py[mj] = r >> 3; px[mj] = r & 7;
    }

    #pragma unroll
    for (int ky = 0; ky < 3; ++ky) {
        #pragma unroll
        for (int kx = 0; kx < 3; ++kx) {
            const int tap = ky*3 + kx;
            #pragma unroll
            for (int kk = 0; kk < 4; ++kk) {
                short8v a[2], bb[4];
                #pragma unroll
                for (int mj = 0; mj < 2; ++mj) {
                    const int pos = (py[mj] + ky)*10 + px[mj] + kx;
                    a[mj] = *(const short8v*)(ldsA + pos*256 + ((16*(kk*4 + kg)) ^ ((pos & 7) << 4)));
                }
                const short* wb = Wt + tap*128 + kk*32 + kg*8;
                #pragma unroll
                for (int nf = 0; nf < 4; ++nf)
                    bb[nf] = *(const short8v*)(wb + (size_t)(wx*64 + nf*16 + lr)*KDIM);
                #pragma unroll
                for (int mj = 0; mj < 2; ++mj)
                    #pragma unroll
                    for (int nf = 0; nf < 4; ++nf)
                        acc[mj][nf] = __builtin_amdgcn_mfma_f32_16x16x32_bf16(a[mj], bb[nf], acc[mj][nf], 0, 0, 0);
            }
        }
    }

    // ---- epilogue: bias + t*E[class], ReLU, bf16 store ----
    #pragma unroll
    for (int mj = 0; mj < 2; ++mj) {
        #pragma unroll
        for (int ri = 0; ri < 4; ++ri) {
            const int r   = (wy*2 + mj)*16 + kg*4 + ri;
            const int gy  = ty + (r >> 3), gx = tx + (r & 7);
            const int cy  = (gy == 0) ? 0 : ((gy == 31) ? 2 : 1);
            const int cx  = (gx == 0) ? 0 : ((gx == 31) ? 2 : 1);
            const int ecl = (cy*3 + cx)*128;
            const size_t obase = ibase + (size_t)((gy << 5) + gx)*128;
            #pragma unroll
            for (int nf = 0; nf < 4; ++nf) {
                const int c = wx*64 + nf*16 + lr;
                float v = fmaxf(acc[mj][nf][ri] + bg[c] + tval*Eg[ecl + c], 0.f);
                out[obase + c] = f2b(v);
            }
        }
    }
}

// ---------------------------------------------------------------------------
// Fused error-norm reduction + controller (last-block-done pattern).
// ---------------------------------------------------------------------------
__global__ __launch_bounds__(256) void err_ctrl_kernel(
    const float* __restrict__ yAp, const float* __restrict__ yBp,
    const u16* __restrict__ k1, const u16* __restrict__ k3,
    const u16* __restrict__ k4, const u16* __restrict__ k5,
    const u16* __restrict__ k6, const u16* __restrict__ k7,
    float* __restrict__ st, double* __restrict__ acc, unsigned* __restrict__ cnt,
    int it)
{
    if (st[3] != 0.0f) return;
    const int flag = (st[5] != 0.0f);
    const float* y  = flag ? yBp : yAp;
    const float* y5 = flag ? yAp : yBp;
    const float dt = st[2];
    const float ER1 = (float)(35.0/384.0 - 5179.0/57600.0);
    const float ER3 = (float)(500.0/1113.0 - 7571.0/16695.0);
    const float ER4 = (float)(125.0/192.0 - 393.0/640.0);
    const float ER5 = (float)(-2187.0/6784.0 + 92097.0/339200.0);
    const float ER6 = (float)(11.0/84.0 - 187.0/2100.0);
    const float ER7 = (float)(-1.0/40.0);
    float lsum = 0.f;
    const int stride = gridDim.x * blockDim.x;
    for (int i = blockIdx.x*blockDim.x + threadIdx.x; i < N8; i += stride) {
        const size_t base = (size_t)i * 8;
        float a[8], c[8], d[8], e[8], f[8], g[8], yv[8], v5[8];
        ld8(k1 + base, a); ld8(k3 + base, c); ld8(k4 + base, d);
        ld8(k5 + base, e); ld8(k6 + base, f); ld8(k7 + base, g);
        *(float4*)(yv)     = *(const float4*)(y + base);
        *(float4*)(yv + 4) = *(const float4*)(y + base + 4);
        *(float4*)(v5)     = *(const float4*)(y5 + base);
        *(float4*)(v5 + 4) = *(const float4*)(y5 + base + 4);
        #pragma unroll
        for (int j = 0; j < 8; ++j) {
            float err = dt*(ER1*a[j] + ER3*c[j] + ER4*d[j] + ER5*e[j] + ER6*f[j] + ER7*g[j]);
            float sc  = 1e-3f + 1e-3f*fmaxf(fabsf(yv[j]), fabsf(v5[j]));
            float rr = err/sc; lsum += rr*rr;
        }
    }
    #pragma unroll
    for (int off = 32; off > 0; off >>= 1) lsum += __shfl_down(lsum, off, 64);
    __shared__ float ws_[4];
    const int wid = threadIdx.x >> 6, lane = threadIdx.x & 63;
    if (lane == 0) ws_[wid] = lsum;
    __syncthreads();
    if (threadIdx.x == 0) {
        const float bs = ws_[0] + ws_[1] + ws_[2] + ws_[3];
        atomicAdd(acc + it, (double)bs);
        __threadfence();
        const unsigned v = atomicAdd(cnt + it, 1u);
        if (v == (unsigned)(EGRID - 1)) {
            __threadfence();
            const double a = atomicAdd(acc + it, 0.0);   // coherent read
            float t = st[0], dtp = st[1], dtc = st[2];
            float en = sqrtf((float)(a / (double)NTOT));
            en = fmaxf(en, 1e-10f);
            const bool accept = (en <= 1.0f);
            float factor = fminf(fmaxf(0.9f * powf(en, -0.2f), 0.2f), 10.0f);
            const bool adv = accept;                     // done is false here
            if (adv) t += dtc;
            dtp = dtc * factor;
            const bool done = (t >= 1.0f - 1e-6f);
            st[0] = t; st[1] = dtp;
            st[2] = fminf(dtp, 1.0f - t);
            st[3] = done ? 1.0f : 0.0f;
            st[4] = adv ? 1.0f : 0.0f;
            if (adv) st[5] = flag ? 0.0f : 1.0f;         // ping-pong flip
        }
    }
}

// ================================ host =====================================

extern "C" void kernel_launch(void* const* d_in, const int* in_sizes, int n_in,
                              void* d_out, int out_size, void* d_ws, size_t ws_size,
                              hipStream_t stream)
{
    const float* xp  = (const float*)d_in[0];
    const float* w1p = (const float*)d_in[1];
    const float* b1p = (const float*)d_in[2];
    const float* w2p = (const float*)d_in[3];
    const float* b2p = (const float*)d_in[4];
    char*  wsp  = (char*)d_ws;
    float* outp = (float*)d_out;

    double*   acc = (double*)wsp;                  // [32] @0
    unsigned* cnt = (unsigned*)(wsp + 256);        // [32] @256
    float*    st  = (float*)(wsp + 512);           // [8]  @512
    float*    E1t = (float*)(wsp + 1024);          // 9*128 f32
    float*    E2t = (float*)(wsp + 5632);
    short*    Wt1 = (short*)(wsp + 10240);         // 128*1152 bf16
    short*    Wt2 = (short*)(wsp + 305152);
    char*     bufs = wsp + 1048576;
    float* yA = (float*)(bufs);                    // 16 MiB
    float* yB = (float*)(bufs + (size_t)NTOT*4);   // 16 MiB
    u16* h  = (u16*)(bufs + (size_t)NTOT*8);
    u16* k1 = (u16*)(bufs + (size_t)NTOT*10);
    u16* k2 = (u16*)(bufs + (size_t)NTOT*12);
    u16* k3 = (u16*)(bufs + (size_t)NTOT*14);
    u16* k4 = (u16*)(bufs + (size_t)NTOT*16);
    u16* k5 = (u16*)(bufs + (size_t)NTOT*18);
    u16* k6 = (u16*)(bufs + (size_t)NTOT*20);
    u16* k7 = (u16*)(bufs + (size_t)NTOT*22);

    const dim3 fgrid(16, 32);    // 16 tiles (4x4 of 8x8) x 32 images = 512
    const dim3 fblk(256);

    init_kernel<<<1, 64, 0, stream>>>(st, acc, cnt);
    prep_kernel<<<10, 256, 0, stream>>>(w1p, Wt1, E1t);
    prep_kernel<<<10, 256, 0, stream>>>(w2p, Wt2, E2t);
    copy_in_kernel<<<2048, 256, 0, stream>>>(yA, xp);

    for (int it = 0; it < MAXIT; ++it) {
        // k1 = f(y, t)
        conv_tile<0,false><<<fgrid, fblk, 0, stream>>>(yA, yB, h, k1,k1,k1,k1,k1, 0,0,0,0,0,
            Wt1, b1p, E1t, h, st, 0.0f);
        conv_tile<-1,false><<<fgrid, fblk, 0, stream>>>(yA, yB, h, k1,k1,k1,k1,k1, 0,0,0,0,0,
            Wt2, b2p, E2t, k1, st, 0.0f);
        // k2
        conv_tile<1,false><<<fgrid, fblk, 0, stream>>>(yA, yB, h, k1,k1,k1,k1,k1, A21,0,0,0,0,
            Wt1, b1p, E1t, h, st, CF2);
        conv_tile<-1,false><<<fgrid, fblk, 0, stream>>>(yA, yB, h, k1,k1,k1,k1,k1, 0,0,0,0,0,
            Wt2, b2p, E2t, k2, st, CF2);
        // k3
        conv_tile<2,false><<<fgrid, fblk, 0, stream>>>(yA, yB, h, k1,k2,k2,k2,k2, A31,A32,0,0,0,
            Wt1, b1p, E1t, h, st, CF3);
        conv_tile<-1,false><<<fgrid, fblk, 0, stream>>>(yA, yB, h, k1,k1,k1,k1,k1, 0,0,0,0,0,
            Wt2, b2p, E2t, k3, st, CF3);
        // k4
        conv_tile<3,false><<<fgrid, fblk, 0, stream>>>(yA, yB, h, k1,k2,k3,k3,k3, A41,A42,A43,0,0,
            Wt1, b1p, E1t, h, st, CF4);
        conv_tile<-1,false><<<fgrid, fblk, 0, stream>>>(yA, yB, h, k1,k1,k1,k1,k1, 0,0,0,0,0,
            Wt2, b2p, E2t, k4, st, CF4);
        // k5
        conv_tile<4,false><<<fgrid, fblk, 0, stream>>>(yA, yB, h, k1,k2,k3,k4,k4, A51,A52,A53,A54,0,
            Wt1, b1p, E1t, h, st, CF5);
        conv_tile<-1,false><<<fgrid, fblk, 0, stream>>>(yA, yB, h, k1,k1,k1,k1,k1, 0,0,0,0,0,
            Wt2, b2p, E2t, k5, st, CF5);
        // k6
        conv_tile<5,false><<<fgrid, fblk, 0, stream>>>(yA, yB, h, k1,k2,k3,k4,k5, A61,A62,A63,A64,A65,
            Wt1, b1p, E1t, h, st, 1.0f);
        conv_tile<-1,false><<<fgrid, fblk, 0, stream>>>(yA, yB, h, k1,k1,k1,k1,k1, 0,0,0,0,0,
            Wt2, b2p, E2t, k6, st, 1.0f);
        // y5 (staged+persisted) -> h = conv1(y5); k7 = conv2(h)
        conv_tile<5,true><<<fgrid, fblk, 0, stream>>>(yA, yB, h, k1,k3,k4,k5,k6, B1c,B3c,B4c,B5c,B6c,
            Wt1, b1p, E1t, h, st, 1.0f);
        conv_tile<-1,false><<<fgrid, fblk, 0, stream>>>(yA, yB, h, k1,k1,k1,k1,k1, 0,0,0,0,0,
            Wt2, b2p, E2t, k7, st, 1.0f);
        // error + controller + ping-pong flip
        err_ctrl_kernel<<<EGRID, 256, 0, stream>>>(yA, yB, k1, k3, k4, k5, k6, k7,
            st, acc, cnt, it);
    }

    copy_out_kernel<<<2048, 256, 0, stream>>>(outp, yA, yB, st);

    (void)in_sizes; (void)n_in; (void)out_size; (void)ws_size;
}